// Round 6
// baseline (104.206 us; speedup 1.0000x reference)
//
#include <hip/hip_runtime.h>

// Bernstein->monomial basis change, degree 5, with input remap t=(x+1)/2 folded in:
// B_i((x+1)/2) = sum_d Mb[i][d] * x^d   (entries exact in fp32: integer/32)
__device__ __constant__ float Mb[6][6] = {
    { 0.03125f, -0.15625f,  0.3125f, -0.3125f,  0.15625f, -0.03125f},
    { 0.15625f, -0.46875f,  0.3125f,  0.3125f, -0.46875f,  0.15625f},
    { 0.3125f,  -0.3125f,  -0.625f,   0.625f,   0.3125f,  -0.3125f },
    { 0.3125f,   0.3125f,  -0.625f,  -0.625f,   0.3125f,   0.3125f },
    { 0.15625f,  0.46875f,  0.3125f, -0.3125f, -0.46875f, -0.15625f},
    { 0.03125f,  0.15625f,  0.3125f,  0.3125f,  0.15625f,  0.03125f},
};

// Kernel 1 (one block): p[3][6][6][6] (Bernstein) -> monomial coeffs
// A[c][i][j][k] in d_ws, q' = 2q-1 folded in. Verified correct in R2.
__global__ __launch_bounds__(256) void ffd_coeffs(const float* __restrict__ p,
                                                  float* __restrict__ A)
{
    __shared__ float b0[648];
    __shared__ float b1[648];
    const int t = threadIdx.x;

    for (int m = t; m < 648; m += 256) b0[m] = p[m];
    __syncthreads();

    // k -> dk  (b0 -> b1)
    for (int m = t; m < 648; m += 256) {
        const int dk = m % 6;
        const int base = (m / 6) * 6;
        float s = 0.f;
        #pragma unroll
        for (int k = 0; k < 6; ++k) s = fmaf(b0[base + k], Mb[k][dk], s);
        b1[m] = s;
    }
    __syncthreads();

    // j -> dj  (b1 -> b0)
    for (int m = t; m < 648; m += 256) {
        const int dk = m % 6;
        const int dj = (m / 6) % 6;
        const int ci = m / 36;               // ci = c*6 + i
        float s = 0.f;
        #pragma unroll
        for (int j = 0; j < 6; ++j) s = fmaf(b1[(ci * 6 + j) * 6 + dk], Mb[j][dj], s);
        b0[m] = s;
    }
    __syncthreads();

    // i -> di, fold in q' = 2q - 1, write to global A.
    for (int m = t; m < 648; m += 256) {
        const int dk = m % 6;
        const int dj = (m / 6) % 6;
        const int di = (m / 36) % 6;
        const int c  = m / 216;
        float s = 0.f;
        #pragma unroll
        for (int i = 0; i < 6; ++i) s = fmaf(b0[((c * 6 + i) * 6 + dj) * 6 + dk], Mb[i][di], s);
        s *= 2.0f;
        if (di == 0 && dj == 0 && dk == 0) s -= 1.0f;
        A[m] = s;
    }
}

typedef float f16v __attribute__((ext_vector_type(16)));
typedef float f4v  __attribute__((ext_vector_type(4)));

// Kernel 2: evaluation, 4 verts/thread. NO LDS (R3 counters showed the LDS
// pipe was the bottleneck: 162 broadcast ds_read_b128/wave ~= 24us of the
// shared pipe). Coefficients come in 36-float blocks via explicit scalar
// loads (s_load_dwordx16/x16/x4 + lgkmcnt) -> SGPRs -> K$-cached, off the
// VALU/LDS pipes entirely; v_fma_f32 takes one SGPR operand directly.
// Fully unrolled (c,ii,jj) -> all indexing compile-time, nothing in scratch.
__global__ __launch_bounds__(256) void ffd_eval(const float* __restrict__ verts,
                                                const float* __restrict__ A,
                                                float* __restrict__ out, int N)
{
    const int t = threadIdx.x;
    const long long v0 = ((long long)blockIdx.x * 256 + t) * 4;
    if (v0 >= N) return;

    float x[4], y[4], z[4];
    const bool full = (v0 + 4 <= N);
    if (full) {
        const float4* vp = (const float4*)(verts + v0 * 3);  // 48B stride -> 16B aligned
        const float4 f0 = vp[0], f1 = vp[1], f2 = vp[2];
        x[0] = f0.x; y[0] = f0.y; z[0] = f0.z;
        x[1] = f0.w; y[1] = f1.x; z[1] = f1.y;
        x[2] = f1.z; y[2] = f1.w; z[2] = f2.x;
        x[3] = f2.y; y[3] = f2.z; z[3] = f2.w;
    } else {
        for (int v = 0; v < 4; ++v) {
            long long n = v0 + v; if (n >= N) n = N - 1;
            x[v] = verts[n * 3 + 0]; y[v] = verts[n * 3 + 1]; z[v] = verts[n * 3 + 2];
        }
    }

    float res[12];
    #pragma unroll
    for (int c = 0; c < 3; ++c) {
        float q[4];
        #pragma unroll
        for (int ii = 0; ii < 6; ++ii) {
            const int i = 5 - ii;
            // 36 coeffs of block (c,i), scalar path: 3 s_loads into SGPRs.
            // Uniform address (kernarg base + constant). Loads+wait in ONE asm
            // with SSA outputs -> uses are dependency-ordered (rule 18 n/a).
            const float* Ab = A + (c * 6 + i) * 36;
            f16v a0, a1; f4v a2;
            asm volatile(
                "s_load_dwordx16 %0, %3, 0x0\n\t"
                "s_load_dwordx16 %1, %3, 0x40\n\t"
                "s_load_dwordx4  %2, %3, 0x80\n\t"
                "s_waitcnt lgkmcnt(0)"
                : "=s"(a0), "=s"(a1), "=s"(a2)
                : "s"(Ab));
            float a[36];
            #pragma unroll
            for (int r = 0; r < 16; ++r) a[r] = a0[r];
            #pragma unroll
            for (int r = 0; r < 16; ++r) a[16 + r] = a1[r];
            #pragma unroll
            for (int r = 0; r < 4; ++r) a[32 + r] = a2[r];

            float tj[4];
            #pragma unroll
            for (int jj = 0; jj < 6; ++jj) {
                const int j = 5 - jj;
                const float* Ak = a + j * 6;
                #pragma unroll
                for (int v = 0; v < 4; ++v) {
                    float s = fmaf(Ak[5], z[v], Ak[4]);
                    s = fmaf(s, z[v], Ak[3]);
                    s = fmaf(s, z[v], Ak[2]);
                    s = fmaf(s, z[v], Ak[1]);
                    s = fmaf(s, z[v], Ak[0]);
                    tj[v] = (jj == 0) ? s : fmaf(tj[v], y[v], s);
                }
            }
            #pragma unroll
            for (int v = 0; v < 4; ++v)
                q[v] = (ii == 0) ? tj[v] : fmaf(q[v], x[v], tj[v]);
        }
        #pragma unroll
        for (int v = 0; v < 4; ++v) res[v * 3 + c] = q[v];  // static -> regs
    }

    if (full) {
        float4* op = (float4*)(out + v0 * 3);
        op[0] = make_float4(res[0], res[1], res[2],  res[3]);
        op[1] = make_float4(res[4], res[5], res[6],  res[7]);
        op[2] = make_float4(res[8], res[9], res[10], res[11]);
    } else {
        for (int v = 0; v < 4; ++v) {
            const long long n = v0 + v;
            if (n < N) {
                out[n * 3 + 0] = res[v * 3 + 0];
                out[n * 3 + 1] = res[v * 3 + 1];
                out[n * 3 + 2] = res[v * 3 + 2];
            }
        }
    }
}

extern "C" void kernel_launch(void* const* d_in, const int* in_sizes, int n_in,
                              void* d_out, int out_size, void* d_ws, size_t ws_size,
                              hipStream_t stream)
{
    const float* verts = (const float*)d_in[0];   // [N,3] fp32
    const float* p     = (const float*)d_in[1];   // [3,6,6,6] fp32
    float* out = (float*)d_out;                   // [1,N,3] fp32
    float* A   = (float*)d_ws;                    // 648 floats of workspace
    const int N = in_sizes[0] / 3;

    ffd_coeffs<<<1, 256, 0, stream>>>(p, A);

    const int nthreads = (N + 3) / 4;
    const int blocks = (nthreads + 255) / 256;
    ffd_eval<<<blocks, 256, 0, stream>>>(verts, A, out, N);
}

// Round 17
// 79.772 us; speedup vs baseline: 1.3063x; 1.3063x over previous
//
#include <hip/hip_runtime.h>

// Bernstein->monomial basis change, degree 5, with input remap t=(x+1)/2 folded in:
// B_i((x+1)/2) = sum_d Mb[i][d] * x^d   (entries exact in fp32: integer/32)
__device__ __constant__ float Mb[6][6] = {
    { 0.03125f, -0.15625f,  0.3125f, -0.3125f,  0.15625f, -0.03125f},
    { 0.15625f, -0.46875f,  0.3125f,  0.3125f, -0.46875f,  0.15625f},
    { 0.3125f,  -0.3125f,  -0.625f,   0.625f,   0.3125f,  -0.3125f },
    { 0.3125f,   0.3125f,  -0.625f,  -0.625f,   0.3125f,   0.3125f },
    { 0.15625f,  0.46875f,  0.3125f, -0.3125f, -0.46875f, -0.15625f},
    { 0.03125f,  0.15625f,  0.3125f,  0.3125f,  0.15625f,  0.03125f},
};

// Single fused kernel. Phase 1: per-block Bernstein->monomial conversion in
// LDS (verified in R0/R3). Phase 2: 8 verts/thread (halves per-vertex LDS
// traffic vs R0: LDS-pipe total ~6us < VALU ~16us -> hideable, unlike R3's
// 2v/t where LDS>VALU). The i-loop is a 3-trip #pragma-unroll-1 loop doing
// TWO coefficient blocks per body with NAMED double buffers aA/aB (rule-20
// safe): the next block's 9 ds_read_b128 issue while the current block's
// 296 FMAs run -> ds latency hidden inside the body, ~15KB code (no I$
// thrash). ds_read_b128 lands directly in FMA operand regs (no s->v movs,
// the R6 mistake). q starts at 0 and merges unconditionally (0*x+tj==tj,
// bitwise identical to the ternary).
__global__ __launch_bounds__(256) void ffd_fused(const float* __restrict__ verts,
                                                 const float* __restrict__ p,
                                                 float* __restrict__ out, int N)
{
    __shared__ __align__(16) float b0[648];
    __shared__ __align__(16) float b1[648];
    const int t = threadIdx.x;

    // ---- Phase 1: separable basis change in LDS ----
    for (int m = t; m < 648; m += 256) b0[m] = p[m];
    __syncthreads();

    for (int m = t; m < 648; m += 256) {           // k -> dk  (b0 -> b1)
        const int dk = m % 6;
        const int base = (m / 6) * 6;
        float s = 0.f;
        #pragma unroll
        for (int k = 0; k < 6; ++k) s = fmaf(b0[base + k], Mb[k][dk], s);
        b1[m] = s;
    }
    __syncthreads();

    for (int m = t; m < 648; m += 256) {           // j -> dj  (b1 -> b0)
        const int dk = m % 6;
        const int dj = (m / 6) % 6;
        const int ci = m / 36;
        float s = 0.f;
        #pragma unroll
        for (int j = 0; j < 6; ++j) s = fmaf(b1[(ci * 6 + j) * 6 + dk], Mb[j][dj], s);
        b0[m] = s;
    }
    __syncthreads();

    for (int m = t; m < 648; m += 256) {           // i -> di, fold q'=2q-1
        const int dk = m % 6;
        const int dj = (m / 6) % 6;
        const int di = (m / 36) % 6;
        const int c  = m / 216;
        float s = 0.f;
        #pragma unroll
        for (int i = 0; i < 6; ++i) s = fmaf(b0[((c * 6 + i) * 6 + dj) * 6 + dk], Mb[i][di], s);
        s *= 2.0f;
        if (di == 0 && dj == 0 && dk == 0) s -= 1.0f;
        b1[m] = s;                                  // b1 = A[c][i][j][k]
    }
    __syncthreads();

    // ---- Phase 2: evaluation, 8 vertices per thread ----
    const long long v0 = ((long long)blockIdx.x * 256 + t) * 8;
    if (v0 >= N) return;

    float x[8], y[8], z[8];
    const bool full = (v0 + 8 <= N);
    if (full) {
        const float4* vp = (const float4*)(verts + v0 * 3);  // 96B/thread, 16B aligned
        float4 f0 = vp[0], f1 = vp[1], f2 = vp[2], f3 = vp[3], f4 = vp[4], f5 = vp[5];
        x[0] = f0.x; y[0] = f0.y; z[0] = f0.z;
        x[1] = f0.w; y[1] = f1.x; z[1] = f1.y;
        x[2] = f1.z; y[2] = f1.w; z[2] = f2.x;
        x[3] = f2.y; y[3] = f2.z; z[3] = f2.w;
        x[4] = f3.x; y[4] = f3.y; z[4] = f3.z;
        x[5] = f3.w; y[5] = f4.x; z[5] = f4.y;
        x[6] = f4.z; y[6] = f4.w; z[6] = f5.x;
        x[7] = f5.y; y[7] = f5.z; z[7] = f5.w;
    } else {
        for (int v = 0; v < 8; ++v) {
            long long n = v0 + v; if (n >= N) n = N - 1;
            x[v] = verts[n * 3 + 0]; y[v] = verts[n * 3 + 1]; z[v] = verts[n * 3 + 2];
        }
    }

    float res[24];
    #pragma unroll
    for (int c = 0; c < 3; ++c) {
        float q[8];
        #pragma unroll
        for (int v = 0; v < 8; ++v) q[v] = 0.f;

        float aA[36], aB[36];
        // prologue: block i=5
        {
            const float4* blk = (const float4*)(b1 + c * 216 + 5 * 36);
            #pragma unroll
            for (int r = 0; r < 9; ++r) {
                const float4 f = blk[r];
                aA[r * 4 + 0] = f.x; aA[r * 4 + 1] = f.y;
                aA[r * 4 + 2] = f.z; aA[r * 4 + 3] = f.w;
            }
        }
        #pragma unroll 1
        for (int m = 0; m < 3; ++m) {
            const int i0 = 5 - 2 * m;
            // issue next block's loads (aB = block i0-1) before computing aA
            {
                const float4* blk = (const float4*)(b1 + c * 216 + (i0 - 1) * 36);
                #pragma unroll
                for (int r = 0; r < 9; ++r) {
                    const float4 f = blk[r];
                    aB[r * 4 + 0] = f.x; aB[r * 4 + 1] = f.y;
                    aB[r * 4 + 2] = f.z; aB[r * 4 + 3] = f.w;
                }
            }
            // compute block i0 with aA
            {
                float tj[8];
                #pragma unroll
                for (int jj = 0; jj < 6; ++jj) {
                    const int j = 5 - jj;
                    const float* Ak = aA + j * 6;
                    #pragma unroll
                    for (int v = 0; v < 8; ++v) {
                        float s = fmaf(Ak[5], z[v], Ak[4]);
                        s = fmaf(s, z[v], Ak[3]);
                        s = fmaf(s, z[v], Ak[2]);
                        s = fmaf(s, z[v], Ak[1]);
                        s = fmaf(s, z[v], Ak[0]);
                        tj[v] = (jj == 0) ? s : fmaf(tj[v], y[v], s);
                    }
                }
                #pragma unroll
                for (int v = 0; v < 8; ++v) q[v] = fmaf(q[v], x[v], tj[v]);
            }
            // prefetch block i0-2 into aA (except last iteration)
            if (m < 2) {
                const float4* blk = (const float4*)(b1 + c * 216 + (i0 - 2) * 36);
                #pragma unroll
                for (int r = 0; r < 9; ++r) {
                    const float4 f = blk[r];
                    aA[r * 4 + 0] = f.x; aA[r * 4 + 1] = f.y;
                    aA[r * 4 + 2] = f.z; aA[r * 4 + 3] = f.w;
                }
            }
            // compute block i0-1 with aB
            {
                float tj[8];
                #pragma unroll
                for (int jj = 0; jj < 6; ++jj) {
                    const int j = 5 - jj;
                    const float* Ak = aB + j * 6;
                    #pragma unroll
                    for (int v = 0; v < 8; ++v) {
                        float s = fmaf(Ak[5], z[v], Ak[4]);
                        s = fmaf(s, z[v], Ak[3]);
                        s = fmaf(s, z[v], Ak[2]);
                        s = fmaf(s, z[v], Ak[1]);
                        s = fmaf(s, z[v], Ak[0]);
                        tj[v] = (jj == 0) ? s : fmaf(tj[v], y[v], s);
                    }
                }
                #pragma unroll
                for (int v = 0; v < 8; ++v) q[v] = fmaf(q[v], x[v], tj[v]);
            }
        }
        #pragma unroll
        for (int v = 0; v < 8; ++v) res[v * 3 + c] = q[v];  // static -> regs
    }

    if (full) {
        float4* op = (float4*)(out + v0 * 3);
        #pragma unroll
        for (int r = 0; r < 6; ++r)
            op[r] = make_float4(res[r * 4 + 0], res[r * 4 + 1],
                                res[r * 4 + 2], res[r * 4 + 3]);
    } else {
        for (int v = 0; v < 8; ++v) {
            const long long n = v0 + v;
            if (n < N) {
                out[n * 3 + 0] = res[v * 3 + 0];
                out[n * 3 + 1] = res[v * 3 + 1];
                out[n * 3 + 2] = res[v * 3 + 2];
            }
        }
    }
}

extern "C" void kernel_launch(void* const* d_in, const int* in_sizes, int n_in,
                              void* d_out, int out_size, void* d_ws, size_t ws_size,
                              hipStream_t stream)
{
    const float* verts = (const float*)d_in[0];   // [N,3] fp32
    const float* p     = (const float*)d_in[1];   // [3,6,6,6] fp32
    float* out = (float*)d_out;                   // [1,N,3] fp32
    const int N = in_sizes[0] / 3;

    const int nthreads = (N + 7) / 8;
    const int blocks = (nthreads + 255) / 256;
    ffd_fused<<<blocks, 256, 0, stream>>>(verts, p, out, N);
}

// Round 18
// 78.955 us; speedup vs baseline: 1.3198x; 1.0103x over previous
//
#include <hip/hip_runtime.h>

// Bernstein->monomial basis change, degree 5, with input remap t=(x+1)/2 folded in:
// B_i((x+1)/2) = sum_d Mb[i][d] * x^d   (entries exact in fp32: integer/32)
__device__ __constant__ float Mb[6][6] = {
    { 0.03125f, -0.15625f,  0.3125f, -0.3125f,  0.15625f, -0.03125f},
    { 0.15625f, -0.46875f,  0.3125f,  0.3125f, -0.46875f,  0.15625f},
    { 0.3125f,  -0.3125f,  -0.625f,   0.625f,   0.3125f,  -0.3125f },
    { 0.3125f,   0.3125f,  -0.625f,  -0.625f,   0.3125f,   0.3125f },
    { 0.15625f,  0.46875f,  0.3125f, -0.3125f, -0.46875f, -0.15625f},
    { 0.03125f,  0.15625f,  0.3125f,  0.3125f,  0.15625f,  0.03125f},
};

typedef float f2 __attribute__((ext_vector_type(2)));

static __device__ __forceinline__ f2 sp(float v) { f2 r; r.x = v; r.y = v; return r; }
#define FMA2(a, b, c) __builtin_elementwise_fma((a), (b), (c))

// Single fused kernel. Phase 1: per-block Bernstein->monomial conversion in
// LDS. Phase 2: 8 verts/thread evaluated as 4 float2 VERTEX PAIRS so every
// Horner step is one v_pk_fma_f32 (packed dual-FP32, VOP3P) instead of one
// v_fma_f32 — halves VALU issue (5184 -> 2592 insts/wave). R17 fit across
// all measured rounds: dur = ~53us fixed (43 fill + ~10 launch gaps) + K;
// K was ~26us for both R0 (4v/t) and R17 (8v/t) -> scalar-FMA issue floor
// dominates, so packed math is the lever. LDS reads unchanged (162 broadcast
// ds_read_b128/wave, double-buffered aA/aB, 3-trip unroll-1 pipeline).
// Packed FMA is single-rounded like fmaf, same per-vertex op order ->
// bitwise-identical output.
__global__ __launch_bounds__(256) void ffd_fused(const float* __restrict__ verts,
                                                 const float* __restrict__ p,
                                                 float* __restrict__ out, int N)
{
    __shared__ __align__(16) float b0[648];
    __shared__ __align__(16) float b1[648];
    const int t = threadIdx.x;

    // ---- Phase 1: separable basis change in LDS ----
    for (int m = t; m < 648; m += 256) b0[m] = p[m];
    __syncthreads();

    for (int m = t; m < 648; m += 256) {           // k -> dk  (b0 -> b1)
        const int dk = m % 6;
        const int base = (m / 6) * 6;
        float s = 0.f;
        #pragma unroll
        for (int k = 0; k < 6; ++k) s = fmaf(b0[base + k], Mb[k][dk], s);
        b1[m] = s;
    }
    __syncthreads();

    for (int m = t; m < 648; m += 256) {           // j -> dj  (b1 -> b0)
        const int dk = m % 6;
        const int dj = (m / 6) % 6;
        const int ci = m / 36;
        float s = 0.f;
        #pragma unroll
        for (int j = 0; j < 6; ++j) s = fmaf(b1[(ci * 6 + j) * 6 + dk], Mb[j][dj], s);
        b0[m] = s;
    }
    __syncthreads();

    for (int m = t; m < 648; m += 256) {           // i -> di, fold q'=2q-1
        const int dk = m % 6;
        const int dj = (m / 6) % 6;
        const int di = (m / 36) % 6;
        const int c  = m / 216;
        float s = 0.f;
        #pragma unroll
        for (int i = 0; i < 6; ++i) s = fmaf(b0[((c * 6 + i) * 6 + dj) * 6 + dk], Mb[i][di], s);
        s *= 2.0f;
        if (di == 0 && dj == 0 && dk == 0) s -= 1.0f;
        b1[m] = s;                                  // b1 = A[c][i][j][k]
    }
    __syncthreads();

    // ---- Phase 2: evaluation, 8 vertices (4 float2 pairs) per thread ----
    const long long v0 = ((long long)blockIdx.x * 256 + t) * 8;
    if (v0 >= N) return;

    f2 x2[4], y2[4], z2[4];
    const bool full = (v0 + 8 <= N);
    if (full) {
        const float4* vp = (const float4*)(verts + v0 * 3);  // 96B/thread, 16B aligned
        float4 f0 = vp[0], f1 = vp[1], f2_ = vp[2], f3 = vp[3], f4 = vp[4], f5 = vp[5];
        x2[0].x = f0.x;  x2[0].y = f0.w;  y2[0].x = f0.y;  y2[0].y = f1.x;  z2[0].x = f0.z;  z2[0].y = f1.y;
        x2[1].x = f1.z;  x2[1].y = f2_.y; y2[1].x = f1.w;  y2[1].y = f2_.z; z2[1].x = f2_.x; z2[1].y = f2_.w;
        x2[2].x = f3.x;  x2[2].y = f3.w;  y2[2].x = f3.y;  y2[2].y = f4.x;  z2[2].x = f3.z;  z2[2].y = f4.y;
        x2[3].x = f4.z;  x2[3].y = f5.y;  y2[3].x = f4.w;  y2[3].y = f5.z;  z2[3].x = f5.x;  z2[3].y = f5.w;
    } else {
        float xs[8], ys[8], zs[8];
        for (int v = 0; v < 8; ++v) {
            long long n = v0 + v; if (n >= N) n = N - 1;
            xs[v] = verts[n * 3 + 0]; ys[v] = verts[n * 3 + 1]; zs[v] = verts[n * 3 + 2];
        }
        #pragma unroll
        for (int pr = 0; pr < 4; ++pr) {
            x2[pr].x = xs[2 * pr]; x2[pr].y = xs[2 * pr + 1];
            y2[pr].x = ys[2 * pr]; y2[pr].y = ys[2 * pr + 1];
            z2[pr].x = zs[2 * pr]; z2[pr].y = zs[2 * pr + 1];
        }
    }

    float res[24];
    #pragma unroll
    for (int c = 0; c < 3; ++c) {
        f2 q[4];
        #pragma unroll
        for (int pr = 0; pr < 4; ++pr) q[pr] = sp(0.f);

        float aA[36], aB[36];
        // prologue: block i=5
        {
            const float4* blk = (const float4*)(b1 + c * 216 + 5 * 36);
            #pragma unroll
            for (int r = 0; r < 9; ++r) {
                const float4 f = blk[r];
                aA[r * 4 + 0] = f.x; aA[r * 4 + 1] = f.y;
                aA[r * 4 + 2] = f.z; aA[r * 4 + 3] = f.w;
            }
        }
        #pragma unroll 1
        for (int m = 0; m < 3; ++m) {
            const int i0 = 5 - 2 * m;
            // issue next block's loads (aB = block i0-1) before computing aA
            {
                const float4* blk = (const float4*)(b1 + c * 216 + (i0 - 1) * 36);
                #pragma unroll
                for (int r = 0; r < 9; ++r) {
                    const float4 f = blk[r];
                    aB[r * 4 + 0] = f.x; aB[r * 4 + 1] = f.y;
                    aB[r * 4 + 2] = f.z; aB[r * 4 + 3] = f.w;
                }
            }
            // compute block i0 with aA (packed: 2 verts per op)
            {
                f2 tj[4];
                #pragma unroll
                for (int jj = 0; jj < 6; ++jj) {
                    const int j = 5 - jj;
                    const float* Ak = aA + j * 6;
                    #pragma unroll
                    for (int pr = 0; pr < 4; ++pr) {
                        f2 s = FMA2(sp(Ak[5]), z2[pr], sp(Ak[4]));
                        s = FMA2(s, z2[pr], sp(Ak[3]));
                        s = FMA2(s, z2[pr], sp(Ak[2]));
                        s = FMA2(s, z2[pr], sp(Ak[1]));
                        s = FMA2(s, z2[pr], sp(Ak[0]));
                        tj[pr] = (jj == 0) ? s : FMA2(tj[pr], y2[pr], s);
                    }
                }
                #pragma unroll
                for (int pr = 0; pr < 4; ++pr) q[pr] = FMA2(q[pr], x2[pr], tj[pr]);
            }
            // prefetch block i0-2 into aA (except last iteration)
            if (m < 2) {
                const float4* blk = (const float4*)(b1 + c * 216 + (i0 - 2) * 36);
                #pragma unroll
                for (int r = 0; r < 9; ++r) {
                    const float4 f = blk[r];
                    aA[r * 4 + 0] = f.x; aA[r * 4 + 1] = f.y;
                    aA[r * 4 + 2] = f.z; aA[r * 4 + 3] = f.w;
                }
            }
            // compute block i0-1 with aB
            {
                f2 tj[4];
                #pragma unroll
                for (int jj = 0; jj < 6; ++jj) {
                    const int j = 5 - jj;
                    const float* Ak = aB + j * 6;
                    #pragma unroll
                    for (int pr = 0; pr < 4; ++pr) {
                        f2 s = FMA2(sp(Ak[5]), z2[pr], sp(Ak[4]));
                        s = FMA2(s, z2[pr], sp(Ak[3]));
                        s = FMA2(s, z2[pr], sp(Ak[2]));
                        s = FMA2(s, z2[pr], sp(Ak[1]));
                        s = FMA2(s, z2[pr], sp(Ak[0]));
                        tj[pr] = (jj == 0) ? s : FMA2(tj[pr], y2[pr], s);
                    }
                }
                #pragma unroll
                for (int pr = 0; pr < 4; ++pr) q[pr] = FMA2(q[pr], x2[pr], tj[pr]);
            }
        }
        #pragma unroll
        for (int pr = 0; pr < 4; ++pr) {            // static -> registers
            res[(2 * pr)     * 3 + c] = q[pr].x;
            res[(2 * pr + 1) * 3 + c] = q[pr].y;
        }
    }

    if (full) {
        float4* op = (float4*)(out + v0 * 3);
        #pragma unroll
        for (int r = 0; r < 6; ++r)
            op[r] = make_float4(res[r * 4 + 0], res[r * 4 + 1],
                                res[r * 4 + 2], res[r * 4 + 3]);
    } else {
        for (int v = 0; v < 8; ++v) {
            const long long n = v0 + v;
            if (n < N) {
                out[n * 3 + 0] = res[v * 3 + 0];
                out[n * 3 + 1] = res[v * 3 + 1];
                out[n * 3 + 2] = res[v * 3 + 2];
            }
        }
    }
}

extern "C" void kernel_launch(void* const* d_in, const int* in_sizes, int n_in,
                              void* d_out, int out_size, void* d_ws, size_t ws_size,
                              hipStream_t stream)
{
    const float* verts = (const float*)d_in[0];   // [N,3] fp32
    const float* p     = (const float*)d_in[1];   // [3,6,6,6] fp32
    float* out = (float*)d_out;                   // [1,N,3] fp32
    const int N = in_sizes[0] / 3;

    const int nthreads = (N + 7) / 8;
    const int blocks = (nthreads + 255) / 256;
    ffd_fused<<<blocks, 256, 0, stream>>>(verts, p, out, N);
}